// Round 1
// baseline (207.989 us; speedup 1.0000x reference)
//
#include <hip/hip_runtime.h>
#include <hip/hip_bf16.h>

typedef __hip_bfloat16 bf16;
typedef __attribute__((ext_vector_type(8))) short short8v;          // 8 bf16 (4 VGPRs)
typedef __attribute__((ext_vector_type(8))) unsigned short ushort8v;
typedef __attribute__((ext_vector_type(4))) unsigned short ushort4v;
typedef __attribute__((ext_vector_type(4))) float float4v;

__device__ __forceinline__ float bfu2f(unsigned short u) {
    union { unsigned int i; float f; } v; v.i = ((unsigned int)u) << 16; return v.f;
}
__device__ __forceinline__ unsigned short f2bfu_rn(float x) {
    union { float f; unsigned int i; } u; u.f = x;
    unsigned int r = (u.i + 0x7FFFu + ((u.i >> 16) & 1u)) >> 16;
    return (unsigned short)r;
}

// ---------- cast+transpose weights: W[k][n] fp32 -> Wt[n][k] bf16. grid (4,4,4) ----------
__global__ __launch_bounds__(256) void cast_wt(
    const float* __restrict__ Wq, const float* __restrict__ Wk,
    const float* __restrict__ Wv, const float* __restrict__ Wp,
    unsigned short* __restrict__ wt)
{
    __shared__ unsigned short tile[64][72];
    const float* W = (blockIdx.z == 0) ? Wq : (blockIdx.z == 1) ? Wk
                   : (blockIdx.z == 2) ? Wv : Wp;
    unsigned short* WT = wt + (size_t)blockIdx.z * 65536;
    const int t = threadIdx.x;
    const int k0 = blockIdx.x * 64, n0 = blockIdx.y * 64;
    {
        const int r = t >> 2, cseg = (t & 3) * 16;
        const float* src = W + (size_t)(k0 + r) * 256 + n0 + cseg;
        #pragma unroll
        for (int j = 0; j < 16; ++j) tile[r][cseg + j] = f2bfu_rn(src[j]);
    }
    __syncthreads();
    {
        const int ch = t & 63, lq = t >> 6;
        ushort8v o0, o1;
        #pragma unroll
        for (int i = 0; i < 8; ++i) o0[i] = tile[lq * 16 + i][ch];
        #pragma unroll
        for (int i = 0; i < 8; ++i) o1[i] = tile[lq * 16 + 8 + i][ch];
        unsigned short* dst = WT + (size_t)(n0 + ch) * 256 + k0 + lq * 16;
        *(ushort8v*)(dst)     = o0;
        *(ushort8v*)(dst + 8) = o1;
    }
}

// ---------- MFMA projection core: 16 m-rows x 128 n-cols per wave ----------
__device__ __forceinline__ void proj_core(
    const float* __restrict__ aptr, const unsigned short* __restrict__ Wt,
    int nc0, int m16, int quad, float4v acc[8])
{
    #pragma unroll
    for (int i = 0; i < 8; ++i) acc[i] = (float4v){0.f, 0.f, 0.f, 0.f};
    #pragma unroll
    for (int ks = 0; ks < 8; ++ks) {
        float4 a0 = *(const float4*)(aptr + ks * 32);
        float4 a1 = *(const float4*)(aptr + ks * 32 + 4);
        short8v af;
        af[0] = (short)f2bfu_rn(a0.x); af[1] = (short)f2bfu_rn(a0.y);
        af[2] = (short)f2bfu_rn(a0.z); af[3] = (short)f2bfu_rn(a0.w);
        af[4] = (short)f2bfu_rn(a1.x); af[5] = (short)f2bfu_rn(a1.y);
        af[6] = (short)f2bfu_rn(a1.z); af[7] = (short)f2bfu_rn(a1.w);
        #pragma unroll
        for (int i = 0; i < 8; ++i) {
            short8v bfr = *(const short8v*)(Wt + (size_t)(nc0 + i * 16 + m16) * 256 + ks * 32 + quad * 8);
            acc[i] = __builtin_amdgcn_mfma_f32_16x16x32_bf16(af, bfr, acc[i], 0, 0, 0);
        }
    }
}

// ---------- fused q/k/v projections. grid 691: [0,19) q, [19,355) k, [355,691) v ----------
__global__ __launch_bounds__(256) void proj_all(
    const float* __restrict__ q, const float* __restrict__ k, const float* __restrict__ v,
    const unsigned short* __restrict__ wt,
    unsigned short* __restrict__ qb, unsigned short* __restrict__ kb,
    unsigned short* __restrict__ vt)
{
    const int t = threadIdx.x;
    const int wave = t >> 6, lane = t & 63;
    const int m16 = lane & 15, quad = lane >> 4;
    const int msub = (wave & 1) * 16;
    const int nc0 = (wave >> 1) * 128;
    const int bx = blockIdx.x;

    float4v acc[8];
    if (bx < 19) {                       // ---- query -> qb (row-major), M=600
        const int m0 = bx * 32;
        const int arow = min(m0 + msub + m16, 599);
        proj_core(q + (size_t)arow * 256 + quad * 8, wt, nc0, m16, quad, acc);
        #pragma unroll
        for (int i = 0; i < 8; ++i)
            #pragma unroll
            for (int r = 0; r < 4; ++r) {
                int m = m0 + msub + quad * 4 + r;
                if (m < 600)
                    qb[(size_t)m * 256 + nc0 + i * 16 + m16] = f2bfu_rn(acc[i][r]);
            }
    } else if (bx < 355) {               // ---- key -> kb (row-major), M=10752
        const int m0 = (bx - 19) * 32;
        proj_core(k + (size_t)(m0 + msub + m16) * 256 + quad * 8, wt + 65536, nc0, m16, quad, acc);
        #pragma unroll
        for (int i = 0; i < 8; ++i)
            #pragma unroll
            for (int r = 0; r < 4; ++r) {
                int m = m0 + msub + quad * 4 + r;
                kb[(size_t)m * 256 + nc0 + i * 16 + m16] = f2bfu_rn(acc[i][r]);
            }
    } else {                             // ---- value -> vt (transposed), M=10752
        const int m0 = (bx - 355) * 32;
        proj_core(v + (size_t)(m0 + msub + m16) * 256 + quad * 8, wt + 131072, nc0, m16, quad, acc);
        const int bb = (m0 >= 5376) ? 1 : 0;
        const int lcol = m0 - bb * 5376 + msub + quad * 4;
        #pragma unroll
        for (int i = 0; i < 8; ++i) {
            const int ch = nc0 + i * 16 + m16;
            ushort4v p;
            #pragma unroll
            for (int r = 0; r < 4; ++r) p[r] = f2bfu_rn(acc[i][r]);
            *(ushort4v*)(vt + (size_t)(bb * 256 + ch) * 5376 + lcol) = p;
        }
    }
}

// ---------- fused QK + softmax + PV + mask-field fold. wave = head. ----------
// grid 456 = 2b x 19 n0 x 12 zz (448 l each), XCD-swizzled so each XCD owns 3
// (b,zz) groups (57 blocks) and keeps their k/vt slices (~1.4 MB) L2-resident.
// Per block: all 8 heads of one (b, 16-row, 448-l) slice -> the 8-head logit
// vector for every pixel is in LDS, so f1/f2/f3+Wm folds happen here and the
// 51.6 MB logits never touch HBM. Wave owns its head's PV slice -> no LDS
// cross-wave reduction; per-zz partial planes summed later in proj_out.
__global__ __launch_bounds__(512) void attn_fused(
    const unsigned short* __restrict__ qb, const unsigned short* __restrict__ kb,
    const unsigned short* __restrict__ vt,
    const float* __restrict__ W1, const float* __restrict__ b1,
    const float* __restrict__ W2, const float* __restrict__ b2,
    const float* __restrict__ W3, const float* __restrict__ b3,
    const float* __restrict__ Wm,
    float* __restrict__ xbp, float* __restrict__ Sp,
    float* __restrict__ g2, float* __restrict__ g3, float* __restrict__ maskp)
{
    __shared__ unsigned short probs[8][16 * 236];   // 60,416 B
    __shared__ float wls[3][64];
    __shared__ float bls[3][8], wmls[3][8];

    const int t = threadIdx.x;
    const int wave = t >> 6, lane = t & 63;

    // XCD-aware decode: 456 = 8 * 57; group = (b*12+zz), 19 n0-tiles per group
    const int i0 = blockIdx.x;
    const int m = (i0 & 7) * 57 + (i0 >> 3);
    const int grp = m / 19, nt = m % 19;
    const int b = grp / 12, zz = grp % 12;
    const int n0 = nt * 16;
    const int l0 = zz * 448;

    if (t < 64) { wls[0][t] = W1[t]; wls[1][t] = W2[t]; wls[2][t] = W3[t]; }
    if (t < 8)  { bls[0][t] = b1[t]; bls[1][t] = b2[t]; bls[2][t] = b3[t];
                  wmls[0][t] = Wm[t]; wmls[1][t] = Wm[8 + t]; wmls[2][t] = Wm[16 + t]; }

    const int m16 = lane & 15, quad = lane >> 4;
    const int h = wave;                 // wave = head
    const float scale = 0.17677669529663687f;   // 1/sqrt(32)

    const unsigned short* qp = qb + (size_t)(b * 300 + min(n0 + m16, 299)) * 256 + h * 32 + quad * 8;
    const short8v qfrag = *(const short8v*)qp;
    const unsigned short* kbase = kb + (size_t)(b * 5376) * 256 + h * 32 + quad * 8;
    const unsigned short* vt0 = vt + (size_t)(b * 256 + h * 32 + m16) * 5376;
    const unsigned short* vt1 = vt0 + (size_t)16 * 5376;
    unsigned short* pw = &probs[wave][0];

    float4v c0 = {0.f, 0.f, 0.f, 0.f};
    float4v c1 = {0.f, 0.f, 0.f, 0.f};
    float sm = 0.f;

    for (int sc = 0; sc < 2; ++sc) {
        const int lc = l0 + sc * 224;

        // ---- QK: 14 tiles of 16 l. A = k (m=l), B = q (n=n). C: row=l, col=n.
        #pragma unroll
        for (int i = 0; i < 14; ++i) {
            const int lcol = lc + i * 16 + m16;
            short8v kf = *(const short8v*)(kbase + (size_t)lcol * 256);
            float4v c = {0.f, 0.f, 0.f, 0.f};
            c = __builtin_amdgcn_mfma_f32_16x16x32_bf16(kf, qfrag, c, 0, 0, 0);
            ushort4v pk;
            #pragma unroll
            for (int r = 0; r < 4; ++r) pk[r] = f2bfu_rn(c[r] * scale);
            *(ushort4v*)(pw + m16 * 236 + i * 16 + quad * 4) = pk;
        }
        __syncthreads();   // all 8 heads' logits visible (also fences wls load)

        // ---- mask-field fold: 16 n x 224 l, 7 px/thread, all 8 heads from LDS
        {
            const int nl = t >> 5;              // 0..15
            const int n = n0 + nl;
            if (n < 300) {
                const int lb = (t & 31) * 7;
                const size_t bn = (size_t)(b * 300 + n);
                #pragma unroll
                for (int j = 0; j < 7; ++j) {
                    const int ll = lb + j;
                    const int p = lc + ll;      // global pixel 0..5375
                    const int lvl = (p >= 4096) + (p >= 5120);
                    float s[8];
                    #pragma unroll
                    for (int hp = 0; hp < 8; ++hp) s[hp] = bfu2f(probs[hp][nl * 236 + ll]);
                    float acc = 0.f;
                    #pragma unroll
                    for (int hh = 0; hh < 8; ++hh) {
                        float f = bls[lvl][hh];
                        #pragma unroll
                        for (int hp = 0; hp < 8; ++hp) f += s[hp] * wls[lvl][hp * 8 + hh];
                        acc += fmaxf(f, 0.f) * wmls[lvl][hh];
                    }
                    if (lvl == 0)      maskp[bn * 4096 + p] = acc;
                    else if (lvl == 1) g2[bn * 1024 + (p - 4096)] = acc;
                    else               g3[bn * 256 + (p - 5120)] = acc;
                }
            }
        }

        // ---- PV: 7 K-steps of 32 l. A[m=n=m16][k=l], exp on read.
        #pragma unroll
        for (int step = 0; step < 7; ++step) {
            const int lloc = step * 32 + quad * 8;
            ushort8v ua = *(const ushort8v*)(pw + m16 * 236 + lloc);
            short8v af;
            #pragma unroll
            for (int j = 0; j < 8; ++j) {
                float e = __expf(bfu2f(ua[j]));
                sm += e;
                af[j] = (short)f2bfu_rn(e);
            }
            const int lg = lc + lloc;
            short8v bb0 = *(const short8v*)(vt0 + lg);
            short8v bb1 = *(const short8v*)(vt1 + lg);
            c0 = __builtin_amdgcn_mfma_f32_16x16x32_bf16(af, bb0, c0, 0, 0, 0);
            c1 = __builtin_amdgcn_mfma_f32_16x16x32_bf16(af, bb1, c1, 0, 0, 0);
        }
        __syncthreads();   // before next subchunk overwrites probs
    }

    // ---- per-wave (= per-head) direct stores, no cross-wave reduction
    sm += __shfl_xor(sm, 16);
    sm += __shfl_xor(sm, 32);
    float* xplane = xbp + (size_t)zz * 153600;
    float* splane = Sp + (size_t)zz * 4800;
    if (lane < 16 && n0 + lane < 300)
        splane[(size_t)(b * 300 + n0 + lane) * 8 + h] = sm;
    #pragma unroll
    for (int r = 0; r < 4; ++r) {
        const int n = n0 + quad * 4 + r;
        if (n < 300) {
            float* o = xplane + (size_t)(b * 300 + n) * 256 + h * 32 + m16;
            o[0]  = c0[r];
            o[16] = c1[r];
        }
    }
}

// ---------- finish: blocks [0,600) mask combine (bilinear + relu, in-place on
// maskpart), blocks [600,638) output projection (16 rows each, 12-plane sum).
__global__ __launch_bounds__(256) void finish(
    const float* __restrict__ g2, const float* __restrict__ g3,
    const float* __restrict__ xbp, const float* __restrict__ Sp,
    const unsigned short* __restrict__ Wtp,
    const float* __restrict__ bpv, const float* __restrict__ bmp,
    float* __restrict__ out)
{
    const int t = threadIdx.x;
    if (blockIdx.x < 600) {
        __shared__ float gs[1280];      // g2s [0,1024), g3s [1024,1280)
        __shared__ float bms;
        const int bn = blockIdx.x;
        if (t == 0) bms = bmp[0];
        ((float4v*)gs)[t] = ((const float4v*)(g2 + (size_t)bn * 1024))[t];
        if (t < 64) ((float4v*)(gs + 1024))[t] = ((const float4v*)(g3 + (size_t)bn * 256))[t];
        __syncthreads();

        float* mp = out + 153600 + (size_t)bn * 4096;
        #pragma unroll
        for (int it = 0; it < 4; ++it) {
            const int p0 = it * 1024 + t * 4;
            float4v mv = *(const float4v*)(mp + p0);
            float4v res;
            #pragma unroll
            for (int pp = 0; pp < 4; ++pp) {
                const int p = p0 + pp;
                const int Y = p >> 6, X = p & 63;
                float acc = mv[pp] + bms;
                {   // g2 bilinear 32 -> 64
                    float ry = fminf(fmaxf(0.5f * Y - 0.25f, 0.f), 31.f);
                    float rx = fminf(fmaxf(0.5f * X - 0.25f, 0.f), 31.f);
                    int y0 = (int)ry, x0 = (int)rx;
                    int y1 = min(y0 + 1, 31), x1 = min(x0 + 1, 31);
                    float wy = ry - (float)y0, wx = rx - (float)x0;
                    acc += (gs[y0 * 32 + x0] * (1.f - wx) + gs[y0 * 32 + x1] * wx) * (1.f - wy)
                         + (gs[y1 * 32 + x0] * (1.f - wx) + gs[y1 * 32 + x1] * wx) * wy;
                }
                {   // g3 bilinear 16 -> 64
                    float ry = fminf(fmaxf(0.25f * Y - 0.375f, 0.f), 15.f);
                    float rx = fminf(fmaxf(0.25f * X - 0.375f, 0.f), 15.f);
                    int y0 = (int)ry, x0 = (int)rx;
                    int y1 = min(y0 + 1, 15), x1 = min(x0 + 1, 15);
                    float wy = ry - (float)y0, wx = rx - (float)x0;
                    acc += (gs[1024 + y0 * 16 + x0] * (1.f - wx) + gs[1024 + y0 * 16 + x1] * wx) * (1.f - wy)
                         + (gs[1024 + y1 * 16 + x0] * (1.f - wx) + gs[1024 + y1 * 16 + x1] * wx) * wy;
            }
                res[pp] = fmaxf(acc, 0.f);
            }
            *(float4v*)(mp + p0) = res;
        }
    } else {
        // ---- proj_out: 38 blocks x 16 rows; combine 12 zz planes + 1/S
        const int bx = blockIdx.x - 600;
        const int wave = t >> 6, lane = t & 63;
        const int m16 = lane & 15, quad = lane >> 4;
        const int nc0 = wave * 64;
        const int m0 = bx * 16;
        const int arow = min(m0 + m16, 599);
        const float* a0p = xbp + (size_t)arow * 256 + quad * 8;

        float4v acc[4];
        #pragma unroll
        for (int i = 0; i < 4; ++i) acc[i] = (float4v){0.f, 0.f, 0.f, 0.f};

        #pragma unroll
        for (int ks = 0; ks < 8; ++ks) {
            float S = 0.f;
            #pragma unroll
            for (int z = 0; z < 12; ++z) S += Sp[(size_t)z * 4800 + arow * 8 + ks];
            const float rS = 1.0f / S;
            float a[8];
            #pragma unroll
            for (int half = 0; half < 2; ++half) {
                float4v x = {0.f, 0.f, 0.f, 0.f};
                #pragma unroll
                for (int z = 0; z < 12; ++z)
                    x += *(const float4v*)(a0p + (size_t)z * 153600 + ks * 32 + half * 4);
                a[half * 4 + 0] = x[0] * rS;
                a[half * 4 + 1] = x[1] * rS;
                a[half * 4 + 2] = x[2] * rS;
                a[half * 4 + 3] = x[3] * rS;
            }
            short8v af;
            #pragma unroll
            for (int j = 0; j < 8; ++j) af[j] = (short)f2bfu_rn(a[j]);
            #pragma unroll
            for (int i = 0; i < 4; ++i) {
                short8v bfr = *(const short8v*)(Wtp + (size_t)(nc0 + i * 16 + m16) * 256 + ks * 32 + quad * 8);
                acc[i] = __builtin_amdgcn_mfma_f32_16x16x32_bf16(af, bfr, acc[i], 0, 0, 0);
            }
        }

        #pragma unroll
        for (int i = 0; i < 4; ++i) {
            const float bv = bpv[nc0 + i * 16 + m16];
            #pragma unroll
            for (int r = 0; r < 4; ++r) {
                int mm = m0 + quad * 4 + r;
                if (mm < 600)
                    out[(size_t)mm * 256 + nc0 + i * 16 + m16] = acc[i][r] + bv;
            }
        }
    }
}

// ---------- launch ----------
extern "C" void kernel_launch(void* const* d_in, const int* in_sizes, int n_in,
                              void* d_out, int out_size, void* d_ws, size_t ws_size,
                              hipStream_t stream) {
    const float* query = (const float*)d_in[0];
    const float* key   = (const float*)d_in[1];
    const float* value = (const float*)d_in[2];
    const float* Wq = (const float*)d_in[5];
    const float* Wk = (const float*)d_in[6];
    const float* Wv = (const float*)d_in[7];
    const float* Wp = (const float*)d_in[8];
    const float* bp = (const float*)d_in[9];
    const float* W1 = (const float*)d_in[10];
    const float* b1 = (const float*)d_in[11];
    const float* W2 = (const float*)d_in[12];
    const float* b2 = (const float*)d_in[13];
    const float* W3 = (const float*)d_in[14];
    const float* b3 = (const float*)d_in[15];
    const float* Wm = (const float*)d_in[16];
    const float* bm = (const float*)d_in[17];
    float* out = (float*)d_out;

    char* ws = (char*)d_ws;
    unsigned short* wt = (unsigned short*)(ws);       // 4*65536 bf16 = 524,288 B
    bf16*  qb   = (bf16*) (ws + 524288);              // 600*256 bf16   = 307,200 B
    bf16*  kb   = (bf16*) (ws + 831488);              // 10752*256 bf16 = 5,505,024 B
    bf16*  vt   = (bf16*) (ws + 6336512);             // 512*5376 bf16  = 5,505,024 B
    float* xbp  = (float*)(ws + 11841536);            // 12*600*256 fp32 = 7,372,800 B
    float* Sp   = (float*)(ws + 19214336);            // 12*4800 fp32    = 230,400 B
    float* g2   = (float*)(ws + 19444736);            // 600*1024 fp32   = 2,457,600 B
    float* g3   = (float*)(ws + 21902336);            // 600*256 fp32    = 614,400 B
    float* maskp = out + 153600;                      // level-1 fold written in-place

    cast_wt<<<dim3(4, 4, 4), 256, 0, stream>>>(Wq, Wk, Wv, Wp, wt);

    proj_all<<<691, 256, 0, stream>>>(query, key, value, wt,
        (unsigned short*)qb, (unsigned short*)kb, (unsigned short*)vt);

    attn_fused<<<456, 512, 0, stream>>>(
        (const unsigned short*)qb, (const unsigned short*)kb, (const unsigned short*)vt,
        W1, b1, W2, b2, W3, b3, Wm, xbp, Sp, g2, g3, maskp);

    finish<<<638, 256, 0, stream>>>(g2, g3, xbp, Sp,
        (const unsigned short*)wt + 196608, bp, bm, out);
}